// Round 1
// baseline (1126.432 us; speedup 1.0000x reference)
//
#include <hip/hip_runtime.h>

// Billeh column GLIF forward: T sequential steps, each = sparse recurrent
// scatter (E=2M synapses) + dense neuron update (N=100K, R=4 receptors).
// Workspace layout (floats): rec_in[4N] | psc[4N] | psc_rise[4N] | z[N] |
// v[N] | r[N] | asc[2N]  = 17N floats ~ 6.8 MB.

constexpr int RR = 4;

__global__ void init_kernel(const float* __restrict__ v0,
                            float* __restrict__ z, float* __restrict__ v,
                            float* __restrict__ r, float* __restrict__ asc,
                            float* __restrict__ psc, float* __restrict__ psc_rise,
                            float* __restrict__ rec_in, int N) {
    int i = blockIdx.x * blockDim.x + threadIdx.x;
    if (i < RR * N) { psc[i] = 0.f; psc_rise[i] = 0.f; rec_in[i] = 0.f; }
    if (i < 2 * N) asc[i] = 0.f;
    if (i < N) { z[i] = 0.f; v[i] = v0[i]; r[i] = 0.f; }
}

__global__ void scatter_kernel(const float* __restrict__ z,
                               const int* __restrict__ pre,
                               const int* __restrict__ post,
                               const int* __restrict__ rc,
                               const float* __restrict__ w,
                               float* __restrict__ rec_in, int E) {
    int e = blockIdx.x * blockDim.x + threadIdx.x;
    if (e >= E) return;
    // z is exactly 0.0f or 1.0f; rec_z forward value == z.
    if (z[pre[e]] != 0.f) {
        atomicAdd(rec_in + (post[e] * RR + rc[e]), w[e]);
    }
}

__global__ void update_kernel(const float4* __restrict__ x_t,
                              float4* __restrict__ rec_in,
                              float4* __restrict__ psc,
                              float4* __restrict__ psc_rise,
                              float* __restrict__ z,
                              float* __restrict__ v,
                              float* __restrict__ r,
                              float2* __restrict__ asc,
                              const float* __restrict__ v_th,
                              const float* __restrict__ v_reset,
                              const float* __restrict__ t_ref,
                              const float* __restrict__ decay,
                              const float* __restrict__ cur_f,
                              const float* __restrict__ e_l,
                              const float2* __restrict__ asc_amps,
                              const float2* __restrict__ asc_decay,
                              const float* __restrict__ syn_d4,
                              const float* __restrict__ psc_i4,
                              float* __restrict__ out_t, int N) {
    int n = blockIdx.x * blockDim.x + threadIdx.x;
    if (n >= N) return;

    float4 ri = rec_in[n];
    float4 xt = x_t[n];
    float4 pr = psc_rise[n];
    float4 pc = psc[n];
    float sd[RR] = {syn_d4[0], syn_d4[1], syn_d4[2], syn_d4[3]};
    float pi[RR] = {psc_i4[0], psc_i4[1], psc_i4[2], psc_i4[3]};
    float riv[RR] = {ri.x, ri.y, ri.z, ri.w};
    float xtv[RR] = {xt.x, xt.y, xt.z, xt.w};
    float prv[RR] = {pr.x, pr.y, pr.z, pr.w};
    float pcv[RR] = {pc.x, pc.y, pc.z, pc.w};

    float in_cur = 0.f;
    float npr[RR], npc[RR];
#pragma unroll
    for (int j = 0; j < RR; j++) {
        float inp = riv[j] + xtv[j];                 // rec_in + x_t
        npr[j] = prv[j] * sd[j] + inp * pi[j];       // new psc_rise
        npc[j] = pcv[j] * sd[j] + sd[j] * prv[j];    // new psc (uses OLD psc_rise, DT=1)
        in_cur += npc[j];                            // sum over receptors (new psc)
    }
    psc_rise[n] = make_float4(npr[0], npr[1], npr[2], npr[3]);
    psc[n]      = make_float4(npc[0], npc[1], npc[2], npc[3]);
    rec_in[n]   = make_float4(0.f, 0.f, 0.f, 0.f);   // re-zero for next step's scatter

    float zn = z[n];
    float2 a  = asc[n];
    float asum = a.x + a.y;                          // OLD asc sum
    float2 ad = asc_decay[n];
    float2 aa = asc_amps[n];
    asc[n] = make_float2(ad.x * a.x + zn * aa.x, ad.y * a.y + zn * aa.y);

    float vth = v_th[n];
    float ic  = in_cur + asum;
    float vv  = decay[n] * v[n] + cur_f[n] * (ic + e_l[n]) + zn * (v_reset[n] - vth);
    float vsc = (vv - vth) / vth;
    float rn  = r[n];
    float nz  = (vsc > 0.f) ? 1.f : 0.f;
    if (rn > 0.f) nz = 0.f;                          // refractory mask (OLD r)
    float nr  = fmaxf(rn - 1.f + nz * t_ref[n], 0.f);

    v[n] = vv;
    r[n] = nr;
    z[n] = nz;
    out_t[n] = nz;
}

extern "C" void kernel_launch(void* const* d_in, const int* in_sizes, int n_in,
                              void* d_out, int out_size, void* d_ws, size_t ws_size,
                              hipStream_t stream) {
    const float* w_rec = (const float*)d_in[0];
    const float* x_ext = (const float*)d_in[1];
    const float* v0    = (const float*)d_in[2];
    const float* v_th  = (const float*)d_in[3];
    const float* v_rst = (const float*)d_in[4];
    const float* t_rf  = (const float*)d_in[5];
    const float* decay = (const float*)d_in[6];
    const float* curf  = (const float*)d_in[7];
    const float* e_l   = (const float*)d_in[8];
    const float* aamps = (const float*)d_in[9];
    const float* adec  = (const float*)d_in[10];
    const float* syn_d = (const float*)d_in[11];
    const float* psc_i = (const float*)d_in[12];
    const int*   pre   = (const int*)d_in[13];
    const int*   post  = (const int*)d_in[14];
    const int*   rc    = (const int*)d_in[15];
    float* out = (float*)d_out;

    const int E = in_sizes[0];
    const int N = in_sizes[2];            // B == 1
    const int T = in_sizes[1] / (N * RR);

    float* ws       = (float*)d_ws;
    float* rec_in   = ws;
    float* psc      = ws + (size_t)4 * N;
    float* psc_rise = ws + (size_t)8 * N;
    float* z        = ws + (size_t)12 * N;
    float* v        = ws + (size_t)13 * N;
    float* r        = ws + (size_t)14 * N;
    float* asc      = ws + (size_t)15 * N;

    init_kernel<<<(RR * N + 255) / 256, 256, 0, stream>>>(
        v0, z, v, r, asc, psc, psc_rise, rec_in, N);

    for (int t = 0; t < T; t++) {
        if (t > 0) {  // z == 0 at t == 0: scatter contributes nothing
            scatter_kernel<<<(E + 255) / 256, 256, 0, stream>>>(
                z, pre, post, rc, w_rec, rec_in, E);
        }
        update_kernel<<<(N + 255) / 256, 256, 0, stream>>>(
            (const float4*)(x_ext + (size_t)t * N * RR),
            (float4*)rec_in, (float4*)psc, (float4*)psc_rise,
            z, v, r, (float2*)asc,
            v_th, v_rst, t_rf, decay, curf, e_l,
            (const float2*)aamps, (const float2*)adec,
            syn_d, psc_i, out + (size_t)t * N, N);
    }
}